// Round 4
// baseline (1036.853 us; speedup 1.0000x reference)
//
#include <hip/hip_runtime.h>
#include <cmath>

#define T_SIZE (1u << 19)

typedef _Float16 h8 __attribute__((ext_vector_type(8)));
typedef _Float16 h4 __attribute__((ext_vector_type(4)));
typedef _Float16 h2 __attribute__((ext_vector_type(2)));
typedef float f4 __attribute__((ext_vector_type(4)));

struct Levels {
    float scale[16];
    int   res[16];
    unsigned dense_mask;
};

// softplus(10z)/10 via hardware exp2/log2
__device__ __forceinline__ float softplus10(float z) {
    float y = z * 10.0f;
    float t = __builtin_amdgcn_exp2f(y * 1.4426950408889634f);          // e^y
    float sp = __builtin_amdgcn_logf(1.0f + t) * 0.069314718055994531f; // ln(1+e^y)/10
    return (y > 20.0f) ? z : sp;
}

// -------- Kernel 0: table f32 -> f16 (4 entries / thread) ----
__global__ __launch_bounds__(256) void convert_table_kernel(
    const float2* __restrict__ t, h2* __restrict__ o, int total4)
{
    int i = blockIdx.x * 256 + threadIdx.x;
    if (i >= total4) return;
    const float2* src = t + (size_t)i * 4;
    h8 r;
#pragma unroll
    for (int j = 0; j < 4; ++j) {
        float2 v = src[j];
        r[2 * j]     = (_Float16)v.x;
        r[2 * j + 1] = (_Float16)v.y;
    }
    *(h8*)(o + (size_t)i * 4) = r;
}

// ---------------- Kernel A: hash-grid encode -> enc2 [16][N] h2 ----------------
// blockIdx.y = level (slow-varying) keeps 1-2 levels hot -> table L2-resident.
// Hash gathers: aligned 8B pair loads (prime_x==1 => even cx pairs adjacent),
// non-temporal (skip L1 line fills; L1 hit rate ~2% at 2MB/level anyway).
__global__ __launch_bounds__(256) void encode_kernel(
    const float* __restrict__ xs, const h2* __restrict__ table,
    h2* __restrict__ enc2, Levels lv, int N)
{
    __shared__ float sx[768];          // 256 points * xyz
    __shared__ float s_scale[16];
    __shared__ int   s_res[16];

    const int i0 = blockIdx.x * 256;
    for (int t = threadIdx.x; t < 768; t += 256) sx[t] = xs[(size_t)i0 * 3 + t];
    if (threadIdx.x < 16) {
        s_scale[threadIdx.x] = lv.scale[threadIdx.x];
        s_res[threadIdx.x]   = lv.res[threadIdx.x];
    }
    __syncthreads();

    const int l = blockIdx.y;          // block-uniform level
    const int i = i0 + threadIdx.x;
    if (i >= N) return;

    const float px = sx[threadIdx.x * 3 + 0];
    const float py = sx[threadIdx.x * 3 + 1];
    const float pz = sx[threadIdx.x * 3 + 2];
    const float s  = s_scale[l];
    const int  res = s_res[l];

    float fx = px * s + 0.5f, fy = py * s + 0.5f, fz = pz * s + 0.5f;
    float gx = floorf(fx), gy = floorf(fy), gz = floorf(fz);
    float wx = fx - gx, wy = fy - gy, wz = fz - gz;
    int cx = (int)gx, cy = (int)gy, cz = (int)gz;

    const h2* tl = table + (size_t)l * T_SIZE;
    // per-combo x0/x1 corner values; combo j: y=(j>>1), z=(j&1)
    float2 vx0[4], vx1[4];

    if ((lv.dense_mask >> l) & 1u) {   // uniform branch
        int r1 = res - 1;
        int x0 = min(cx, r1), x1 = min(cx + 1, r1);
        int y0 = min(cy, r1), y1 = min(cy + 1, r1);
        int z0 = min(cz, r1), z1 = min(cz + 1, r1);
        int rr = res * res;
        int base00 = y0 * res + z0 * rr;
        int base01 = y0 * res + z1 * rr;
        int base10 = y1 * res + z0 * rr;
        int base11 = y1 * res + z1 * rr;
        int bases[4] = {base00, base01, base10, base11};
#pragma unroll
        for (int j = 0; j < 4; ++j) {
            h2 a = tl[x0 + bases[j]];
            h2 b = tl[x1 + bases[j]];
            vx0[j] = make_float2((float)a[0], (float)a[1]);
            vx1[j] = make_float2((float)b[0], (float)b[1]);
        }
    } else {
        unsigned hy0 = (unsigned)cy * 2654435761u, hy1 = (unsigned)(cy + 1) * 2654435761u;
        unsigned hz0 = (unsigned)cz * 805459861u,  hz1 = (unsigned)(cz + 1) * 805459861u;
        unsigned Y[4] = {hy0 ^ hz0, hy0 ^ hz1, hy1 ^ hz0, hy1 ^ hz1};
        const bool odd = (cx & 1);
        const unsigned M = T_SIZE - 1;
#pragma unroll
        for (int j = 0; j < 4; ++j) {
            unsigned h0m = ((unsigned)cx ^ Y[j]) & M;
            unsigned h1m = ((unsigned)(cx + 1) ^ Y[j]) & M;
            unsigned pairIdx = h0m & ~1u;
            h4 pr = __builtin_nontemporal_load((const h4*)(tl + pairIdx)); // 8B aligned
            float2 lo = make_float2((float)pr[0], (float)pr[1]);
            float2 hi = make_float2((float)pr[2], (float)pr[3]);
            bool h0hi = (h0m & 1u);
            vx0[j] = h0hi ? hi : lo;
            if (odd) {                 // masked 4B load (~half the lanes)
                h2 v = __builtin_nontemporal_load(tl + h1m);
                vx1[j] = make_float2((float)v[0], (float)v[1]);
            } else {
                vx1[j] = h0hi ? lo : hi;   // h1m = h0m ^ 1
            }
        }
    }

    float wx0 = 1.f - wx, wy0 = 1.f - wy, wz0 = 1.f - wz;
    // combo weights without x: j=0:(y0,z0) 1:(y0,z1) 2:(y1,z0) 3:(y1,z1)
    float wyz[4] = {wy0 * wz0, wy0 * wz, wy * wz0, wy * wz};
    float f0 = 0.f, f1 = 0.f;
#pragma unroll
    for (int j = 0; j < 4; ++j) {
        float w0 = wx0 * wyz[j], w1 = wx * wyz[j];
        f0 += w0 * vx0[j].x + w1 * vx1[j].x;
        f1 += w0 * vx0[j].y + w1 * vx1[j].y;
    }

    h2 r;
    r[0] = (_Float16)f0;
    r[1] = (_Float16)f1;
    enc2[(size_t)l * N + i] = r;       // coalesced 4B store
}

// ---------------- Kernel B: fused MLP via f16 MFMA ----------------
// Each wave's whole tile pipeline touches only its own 64 sAct rows ->
// NO per-tile barriers. Weight LDS overlapped with sAct (weights live in
// registers after prologue): 37KB LDS -> 4 blocks/CU.
// A-layout: A[m=lane&15][k=quad*8+j]; D-layout: D[row=quad*4+r][col=lane&15].
__global__ __launch_bounds__(256, 3) void mlp_kernel(
    const h2* __restrict__ enc2,
    const float* __restrict__ w1, const float* __restrict__ w2,
    const float* __restrict__ w3, const float* __restrict__ w4,
    float* __restrict__ out, int tiles, int N)
{
    constexpr int W1R = 40;
    constexpr int W2R = 72;
    constexpr int AR  = 72;
    __shared__ __align__(16) char smem[256 * AR * 2];   // 36864B: staging ∪ sAct
    __shared__ float sW4[64];

    _Float16* sAct = (_Float16*)smem;
    _Float16* sW1  = (_Float16*)smem;                        // 64*W1R*2 = 5120B
    _Float16* sW2  = (_Float16*)(smem + 5120);               // 9216B
    _Float16* sW3  = (_Float16*)(smem + 5120 + 9216);        // 9216B

    const int tid = threadIdx.x;
    for (int i = tid; i < 64 * 32; i += 256) sW1[(i >> 5) * W1R + (i & 31)] = (_Float16)w1[i];
    for (int i = tid; i < 64 * 64; i += 256) sW2[(i >> 6) * W2R + (i & 63)] = (_Float16)w2[i];
    for (int i = tid; i < 64 * 64; i += 256) sW3[(i >> 6) * W2R + (i & 63)] = (_Float16)w3[i];
    if (tid < 64) sW4[tid] = w4[tid];
    __syncthreads();

    const int wave = tid >> 6;
    const int lane = tid & 63;
    const int lrow = lane & 15;
    const int quad = lane >> 4;
    const int waveRow = wave * 64;
    const f4 zero = {0.f, 0.f, 0.f, 0.f};

    // weight fragments -> registers (then staging LDS is dead)
    h8 b1[4];
#pragma unroll
    for (int tn = 0; tn < 4; ++tn)
        b1[tn] = *(const h8*)&sW1[(lrow + 16 * tn) * W1R + quad * 8];
    h8 b2[2][4], b3[2][4];
#pragma unroll
    for (int kh = 0; kh < 2; ++kh)
#pragma unroll
        for (int tn = 0; tn < 4; ++tn) {
            b2[kh][tn] = *(const h8*)&sW2[(lrow + 16 * tn) * W2R + kh * 32 + quad * 8];
            b3[kh][tn] = *(const h8*)&sW3[(lrow + 16 * tn) * W2R + kh * 32 + quad * 8];
        }
    __syncthreads();   // all frag reads done before sAct overwrites staging

    for (int it = 0; it < tiles; ++it) {
        const int blockPt = (blockIdx.x * tiles + it) * 256;

        // ---- Layer 1: enc2 (level-major [16][N]) @ w1^T ----
#pragma unroll
        for (int t = 0; t < 4; ++t) {
            const int rowg = blockPt + waveRow + t * 16 + lrow;
            h8 a;
#pragma unroll
            for (int d = 0; d < 4; ++d) {
                h2 p = enc2[(size_t)(4 * quad + d) * N + rowg];   // 4B coalesced
                a[2 * d]     = p[0];
                a[2 * d + 1] = p[1];
            }
#pragma unroll
            for (int tn = 0; tn < 4; ++tn) {
                f4 acc = __builtin_amdgcn_mfma_f32_16x16x32_f16(a, b1[tn], zero, 0, 0, 0);
#pragma unroll
                for (int r = 0; r < 4; ++r) {
                    int prow = waveRow + t * 16 + quad * 4 + r;
                    sAct[prow * AR + tn * 16 + lrow] = (_Float16)softplus10(acc[r]);
                }
            }
        }
        // no barrier: wave-private rows

        // ---- Layers 2 & 3 ----
#pragma unroll
        for (int layer = 0; layer < 2; ++layer) {
#pragma unroll
            for (int t = 0; t < 4; ++t) {
                const int arow = (waveRow + t * 16 + lrow) * AR;
                h8 a0 = *(const h8*)&sAct[arow + quad * 8];
                h8 a1 = *(const h8*)&sAct[arow + 32 + quad * 8];
                f4 accs[4];
#pragma unroll
                for (int tn = 0; tn < 4; ++tn) {
                    f4 acc = __builtin_amdgcn_mfma_f32_16x16x32_f16(
                        a0, layer ? b3[0][tn] : b2[0][tn], zero, 0, 0, 0);
                    acc = __builtin_amdgcn_mfma_f32_16x16x32_f16(
                        a1, layer ? b3[1][tn] : b2[1][tn], acc, 0, 0, 0);
                    accs[tn] = acc;
                }
#pragma unroll
                for (int tn = 0; tn < 4; ++tn)
#pragma unroll
                    for (int r = 0; r < 4; ++r)
                        sAct[(waveRow + t * 16 + quad * 4 + r) * AR + tn * 16 + lrow] =
                            (_Float16)softplus10(accs[tn][r]);
            }
        }

        // ---- Layer 4: per-thread dot with w4 (own row == own wave's rows) ----
        float sum = 0.f;
#pragma unroll
        for (int k8 = 0; k8 < 8; ++k8) {
            h8 a = *(const h8*)&sAct[tid * AR + k8 * 8];
#pragma unroll
            for (int j = 0; j < 8; ++j) sum += (float)a[j] * sW4[k8 * 8 + j];
        }
        out[blockPt + tid] = sum;
    }
}

// Fallback encode (f32 table) if workspace too small for f16 table
__global__ __launch_bounds__(256) void encode_kernel_f32(
    const float* __restrict__ xs, const float2* __restrict__ table,
    h2* __restrict__ enc2, Levels lv, int N)
{
    const int i = blockIdx.x * 256 + threadIdx.x;
    const int l = blockIdx.y;
    if (i >= N) return;
    float px = xs[3 * i], py = xs[3 * i + 1], pz = xs[3 * i + 2];
    float s = lv.scale[l];
    int res = lv.res[l];
    float fx = px * s + 0.5f, fy = py * s + 0.5f, fz = pz * s + 0.5f;
    float gx = floorf(fx), gy = floorf(fy), gz = floorf(fz);
    float wx = fx - gx, wy = fy - gy, wz = fz - gz;
    int cx = (int)gx, cy = (int)gy, cz = (int)gz;
    unsigned idx[8];
    if ((lv.dense_mask >> l) & 1u) {
        int r1 = res - 1;
        int x0 = min(cx, r1), x1 = min(cx + 1, r1);
        int y0 = min(cy, r1), y1 = min(cy + 1, r1);
        int z0 = min(cz, r1), z1 = min(cz + 1, r1);
        int rr = res * res;
        idx[0] = x0 + y0 * res + z0 * rr; idx[1] = x0 + y0 * res + z1 * rr;
        idx[2] = x0 + y1 * res + z0 * rr; idx[3] = x0 + y1 * res + z1 * rr;
        idx[4] = x1 + y0 * res + z0 * rr; idx[5] = x1 + y0 * res + z1 * rr;
        idx[6] = x1 + y1 * res + z0 * rr; idx[7] = x1 + y1 * res + z1 * rr;
    } else {
        unsigned hx0 = (unsigned)cx, hx1 = (unsigned)(cx + 1);
        unsigned hy0 = (unsigned)cy * 2654435761u, hy1 = (unsigned)(cy + 1) * 2654435761u;
        unsigned hz0 = (unsigned)cz * 805459861u,  hz1 = (unsigned)(cz + 1) * 805459861u;
        idx[0] = (hx0^hy0^hz0) & (T_SIZE-1); idx[1] = (hx0^hy0^hz1) & (T_SIZE-1);
        idx[2] = (hx0^hy1^hz0) & (T_SIZE-1); idx[3] = (hx0^hy1^hz1) & (T_SIZE-1);
        idx[4] = (hx1^hy0^hz0) & (T_SIZE-1); idx[5] = (hx1^hy0^hz1) & (T_SIZE-1);
        idx[6] = (hx1^hy1^hz0) & (T_SIZE-1); idx[7] = (hx1^hy1^hz1) & (T_SIZE-1);
    }
    const float2* tl = table + (size_t)l * T_SIZE;
    float wx0 = 1.f - wx, wy0 = 1.f - wy, wz0 = 1.f - wz;
    float wcs[8] = {wx0*wy0*wz0, wx0*wy0*wz, wx0*wy*wz0, wx0*wy*wz,
                    wx*wy0*wz0,  wx*wy0*wz,  wx*wy*wz0,  wx*wy*wz};
    float f0 = 0.f, f1 = 0.f;
#pragma unroll
    for (int c = 0; c < 8; ++c) {
        float2 v = tl[idx[c]];
        f0 += wcs[c] * v.x; f1 += wcs[c] * v.y;
    }
    h2 r; r[0] = (_Float16)f0; r[1] = (_Float16)f1;
    enc2[(size_t)l * N + i] = r;
}

extern "C" void kernel_launch(void* const* d_in, const int* in_sizes, int n_in,
                              void* d_out, int out_size, void* d_ws, size_t ws_size,
                              hipStream_t stream) {
    const float* x     = (const float*)d_in[0];
    const float* table = (const float*)d_in[1];
    const float* w1    = (const float*)d_in[2];
    const float* w2    = (const float*)d_in[3];
    const float* w3    = (const float*)d_in[4];
    const float* w4    = (const float*)d_in[5];
    float* out = (float*)d_out;
    const int N = in_sizes[0] / 3;                 // 1<<20

    Levels lv;
    lv.dense_mask = 0;
    const double pls = exp2(log2(2048.0 / 16.0) / 15.0);
    const double lg  = log2(pls);
    for (int l = 0; l < 16; ++l) {
        double sc = exp2((double)l * lg) * 16.0 - 1.0;
        int res = (int)ceil(sc) + 1;
        lv.scale[l] = (float)sc;
        lv.res[l]   = res;
        if ((long long)res * res * res <= (long long)T_SIZE) lv.dense_mask |= (1u << l);
    }

    const size_t encBytes   = (size_t)16 * N * 4;        // 64 MB
    const size_t tableBytes = (size_t)16 * T_SIZE * 4;   // 33.5 MB
    h2* enc2 = (h2*)d_ws;

    const int ptBlocks = (N + 255) / 256;                // 4096
    dim3 encGrid(ptBlocks, 16);                          // y = level

    if (ws_size >= encBytes + tableBytes) {
        h2* table16 = (h2*)((char*)d_ws + encBytes);
        const int total4 = 16 * T_SIZE / 4;
        hipLaunchKernelGGL(convert_table_kernel, dim3((total4 + 255) / 256), dim3(256), 0,
                           stream, (const float2*)table, table16, total4);
        hipLaunchKernelGGL(encode_kernel, encGrid, dim3(256), 0, stream,
                           x, (const h2*)table16, enc2, lv, N);
    } else {
        hipLaunchKernelGGL(encode_kernel_f32, encGrid, dim3(256), 0, stream,
                           x, (const float2*)table, enc2, lv, N);
    }

    const int mlpBlocks = 1024;                          // ~4 blocks/CU
    const int tiles = N / 256 / mlpBlocks;               // 4
    hipLaunchKernelGGL(mlp_kernel, dim3(mlpBlocks), dim3(256), 0, stream,
                       enc2, w1, w2, w3, w4, out, tiles, N);
}

// Round 5
// 539.133 us; speedup vs baseline: 1.9232x; 1.9232x over previous
//
#include <hip/hip_runtime.h>
#include <cmath>

#define T_SIZE (1u << 19)

typedef _Float16 h8 __attribute__((ext_vector_type(8)));
typedef _Float16 h4 __attribute__((ext_vector_type(4)));
typedef _Float16 h2 __attribute__((ext_vector_type(2)));
typedef float f4 __attribute__((ext_vector_type(4)));

struct Levels {
    float scale[16];
    int   res[16];
    unsigned dense_mask;
};

// softplus(10z)/10, branch-free: ln(1+e^y)/10 -> z automatically once e^y>>1.
// fmin clamp only guards f32 overflow (activations here are O(0.1), cap irrelevant).
__device__ __forceinline__ float softplus10(float z) {
    float e = __builtin_amdgcn_exp2f(fminf(z * 14.426950408889634f, 126.0f)); // e^{10z}
    return __builtin_amdgcn_logf(1.0f + e) * 0.069314718055994531f;           // log2->ln/10
}

// -------- Kernel 0: table f32 -> f16 (4 entries / thread) ----
__global__ __launch_bounds__(256) void convert_table_kernel(
    const float2* __restrict__ t, h2* __restrict__ o, int total4)
{
    int i = blockIdx.x * 256 + threadIdx.x;
    if (i >= total4) return;
    const float2* src = t + (size_t)i * 4;
    h8 r;
#pragma unroll
    for (int j = 0; j < 4; ++j) {
        float2 v = src[j];
        r[2 * j]     = (_Float16)v.x;
        r[2 * j + 1] = (_Float16)v.y;
    }
    *(h8*)(o + (size_t)i * 4) = r;
}

// ---------------- Kernel A: hash-grid encode -> enc2 [16][N] h2 ----------------
// blockIdx.y = level (slow-varying) keeps 1-2 levels hot -> table L2-resident.
// Pair trick: x-corners differ by ^1 (hash, prime_x==1) or +1 (dense), so one
// aligned 8B load covers both corners for ~half the lanes; masked 4B load for rest.
// Plain (cached) loads — nt destroyed L2 residency in R4.
__global__ __launch_bounds__(256) void encode_kernel(
    const float* __restrict__ xs, const h2* __restrict__ table,
    h2* __restrict__ enc2, Levels lv, int N)
{
    __shared__ float sx[768];          // 256 points * xyz
    __shared__ float s_scale[16];
    __shared__ int   s_res[16];

    const int i0 = blockIdx.x * 256;
    for (int t = threadIdx.x; t < 768; t += 256) sx[t] = xs[(size_t)i0 * 3 + t];
    if (threadIdx.x < 16) {
        s_scale[threadIdx.x] = lv.scale[threadIdx.x];
        s_res[threadIdx.x]   = lv.res[threadIdx.x];
    }
    __syncthreads();

    const int l = blockIdx.y;          // block-uniform level
    const int i = i0 + threadIdx.x;
    if (i >= N) return;

    const float px = sx[threadIdx.x * 3 + 0];
    const float py = sx[threadIdx.x * 3 + 1];
    const float pz = sx[threadIdx.x * 3 + 2];
    const float s  = s_scale[l];
    const int  res = s_res[l];

    float fx = px * s + 0.5f, fy = py * s + 0.5f, fz = pz * s + 0.5f;
    float gx = floorf(fx), gy = floorf(fy), gz = floorf(fz);
    float wx = fx - gx, wy = fy - gy, wz = fz - gz;
    int cx = (int)gx, cy = (int)gy, cz = (int)gz;

    const h2* tl = table + (size_t)l * T_SIZE;
    float2 vx0[4], vx1[4];             // combo j: y=(j>>1), z=(j&1)

    if ((lv.dense_mask >> l) & 1u) {   // uniform branch
        int r1 = res - 1;
        int x0 = min(cx, r1), x1 = min(cx + 1, r1);
        int y0 = min(cy, r1), y1 = min(cy + 1, r1);
        int z0 = min(cz, r1), z1 = min(cz + 1, r1);
        int rr = res * res;
        int bases[4] = {y0 * res + z0 * rr, y0 * res + z1 * rr,
                        y1 * res + z0 * rr, y1 * res + z1 * rr};
#pragma unroll
        for (int j = 0; j < 4; ++j) {
            int idx0 = x0 + bases[j];
            int idx1 = x1 + bases[j];
            h4 pr = *(const h4*)(tl + (idx0 & ~1));   // aligned 8B pair
            float2 lo = make_float2((float)pr[0], (float)pr[1]);
            float2 hi = make_float2((float)pr[2], (float)pr[3]);
            bool hi0 = idx0 & 1;
            vx0[j] = hi0 ? hi : lo;
            if (hi0 && idx1 != idx0) {                // masked 4B load (~half lanes)
                h2 v = tl[idx1];
                vx1[j] = make_float2((float)v[0], (float)v[1]);
            } else {
                vx1[j] = (idx1 == idx0) ? vx0[j] : hi; // even idx0: pair covers idx0+1
            }
        }
    } else {
        unsigned hy0 = (unsigned)cy * 2654435761u, hy1 = (unsigned)(cy + 1) * 2654435761u;
        unsigned hz0 = (unsigned)cz * 805459861u,  hz1 = (unsigned)(cz + 1) * 805459861u;
        unsigned Y[4] = {hy0 ^ hz0, hy0 ^ hz1, hy1 ^ hz0, hy1 ^ hz1};
        const bool odd = (cx & 1);
        const unsigned M = T_SIZE - 1;
#pragma unroll
        for (int j = 0; j < 4; ++j) {
            unsigned h0m = ((unsigned)cx ^ Y[j]) & M;
            unsigned h1m = ((unsigned)(cx + 1) ^ Y[j]) & M;
            h4 pr = *(const h4*)(tl + (h0m & ~1u));   // aligned 8B pair
            float2 lo = make_float2((float)pr[0], (float)pr[1]);
            float2 hi = make_float2((float)pr[2], (float)pr[3]);
            bool h0hi = (h0m & 1u);
            vx0[j] = h0hi ? hi : lo;
            if (odd) {                                // masked 4B load (~half lanes)
                h2 v = tl[h1m];
                vx1[j] = make_float2((float)v[0], (float)v[1]);
            } else {
                vx1[j] = h0hi ? lo : hi;              // even cx: h1m = h0m ^ 1
            }
        }
    }

    float wx0 = 1.f - wx, wy0 = 1.f - wy, wz0 = 1.f - wz;
    float wyz[4] = {wy0 * wz0, wy0 * wz, wy * wz0, wy * wz};
    float f0 = 0.f, f1 = 0.f;
#pragma unroll
    for (int j = 0; j < 4; ++j) {
        float w0 = wx0 * wyz[j], w1 = wx * wyz[j];
        f0 += w0 * vx0[j].x + w1 * vx1[j].x;
        f1 += w0 * vx0[j].y + w1 * vx1[j].y;
    }

    h2 r;
    r[0] = (_Float16)f0;
    r[1] = (_Float16)f1;
    enc2[(size_t)l * N + i] = r;       // coalesced 4B store
}

// ---------------- Kernel B: fused MLP via f16 MFMA ----------------
// Wave-private sAct rows -> no per-tile barriers. Weight staging LDS overlapped
// with sAct (weights live in registers after prologue).
// A-layout: A[m=lane&15][k=quad*8+j]; D-layout: D[row=quad*4+r][col=lane&15].
__global__ __launch_bounds__(256, 3) void mlp_kernel(
    const h2* __restrict__ enc2,
    const float* __restrict__ w1, const float* __restrict__ w2,
    const float* __restrict__ w3, const float* __restrict__ w4,
    float* __restrict__ out, int tiles, int N)
{
    constexpr int W1R = 40;
    constexpr int W2R = 72;
    constexpr int AR  = 72;
    __shared__ __align__(16) char smem[256 * AR * 2];   // 36864B: staging ∪ sAct
    __shared__ float sW4[64];

    _Float16* sAct = (_Float16*)smem;
    _Float16* sW1  = (_Float16*)smem;                        // 5120B
    _Float16* sW2  = (_Float16*)(smem + 5120);               // 9216B
    _Float16* sW3  = (_Float16*)(smem + 5120 + 9216);        // 9216B

    const int tid = threadIdx.x;
    for (int i = tid; i < 64 * 32; i += 256) sW1[(i >> 5) * W1R + (i & 31)] = (_Float16)w1[i];
    for (int i = tid; i < 64 * 64; i += 256) sW2[(i >> 6) * W2R + (i & 63)] = (_Float16)w2[i];
    for (int i = tid; i < 64 * 64; i += 256) sW3[(i >> 6) * W2R + (i & 63)] = (_Float16)w3[i];
    if (tid < 64) sW4[tid] = w4[tid];
    __syncthreads();

    const int wave = tid >> 6;
    const int lane = tid & 63;
    const int lrow = lane & 15;
    const int quad = lane >> 4;
    const int waveRow = wave * 64;
    const f4 zero = {0.f, 0.f, 0.f, 0.f};

    // weight fragments -> registers (then staging LDS is dead)
    h8 b1[4];
#pragma unroll
    for (int tn = 0; tn < 4; ++tn)
        b1[tn] = *(const h8*)&sW1[(lrow + 16 * tn) * W1R + quad * 8];
    h8 b2[2][4], b3[2][4];
#pragma unroll
    for (int kh = 0; kh < 2; ++kh)
#pragma unroll
        for (int tn = 0; tn < 4; ++tn) {
            b2[kh][tn] = *(const h8*)&sW2[(lrow + 16 * tn) * W2R + kh * 32 + quad * 8];
            b3[kh][tn] = *(const h8*)&sW3[(lrow + 16 * tn) * W2R + kh * 32 + quad * 8];
        }
    __syncthreads();   // all frag reads done before sAct overwrites staging

    for (int it = 0; it < tiles; ++it) {
        const int blockPt = (blockIdx.x * tiles + it) * 256;

        // ---- Layer 1: enc2 (level-major [16][N]) @ w1^T ----
#pragma unroll
        for (int t = 0; t < 4; ++t) {
            const int rowg = blockPt + waveRow + t * 16 + lrow;
            h8 a;
#pragma unroll
            for (int d = 0; d < 4; ++d) {
                h2 p = enc2[(size_t)(4 * quad + d) * N + rowg];   // 4B coalesced
                a[2 * d]     = p[0];
                a[2 * d + 1] = p[1];
            }
#pragma unroll
            for (int tn = 0; tn < 4; ++tn) {
                f4 acc = __builtin_amdgcn_mfma_f32_16x16x32_f16(a, b1[tn], zero, 0, 0, 0);
#pragma unroll
                for (int r = 0; r < 4; ++r) {
                    int prow = waveRow + t * 16 + quad * 4 + r;
                    sAct[prow * AR + tn * 16 + lrow] = (_Float16)softplus10(acc[r]);
                }
            }
        }
        // no barrier: wave-private rows

        // ---- Layers 2 & 3 ----
#pragma unroll
        for (int layer = 0; layer < 2; ++layer) {
#pragma unroll
            for (int t = 0; t < 4; ++t) {
                const int arow = (waveRow + t * 16 + lrow) * AR;
                h8 a0 = *(const h8*)&sAct[arow + quad * 8];
                h8 a1 = *(const h8*)&sAct[arow + 32 + quad * 8];
                f4 accs[4];
#pragma unroll
                for (int tn = 0; tn < 4; ++tn) {
                    f4 acc = __builtin_amdgcn_mfma_f32_16x16x32_f16(
                        a0, layer ? b3[0][tn] : b2[0][tn], zero, 0, 0, 0);
                    acc = __builtin_amdgcn_mfma_f32_16x16x32_f16(
                        a1, layer ? b3[1][tn] : b2[1][tn], acc, 0, 0, 0);
                    accs[tn] = acc;
                }
#pragma unroll
                for (int tn = 0; tn < 4; ++tn)
#pragma unroll
                    for (int r = 0; r < 4; ++r)
                        sAct[(waveRow + t * 16 + quad * 4 + r) * AR + tn * 16 + lrow] =
                            (_Float16)softplus10(accs[tn][r]);
            }
        }

        // ---- Layer 4: per-thread dot with w4 ----
        float sum = 0.f;
#pragma unroll
        for (int k8 = 0; k8 < 8; ++k8) {
            h8 a = *(const h8*)&sAct[tid * AR + k8 * 8];
#pragma unroll
            for (int j = 0; j < 8; ++j) sum += (float)a[j] * sW4[k8 * 8 + j];
        }
        out[blockPt + tid] = sum;
    }
}

// Fallback encode (f32 table) if workspace too small for f16 table
__global__ __launch_bounds__(256) void encode_kernel_f32(
    const float* __restrict__ xs, const float2* __restrict__ table,
    h2* __restrict__ enc2, Levels lv, int N)
{
    const int i = blockIdx.x * 256 + threadIdx.x;
    const int l = blockIdx.y;
    if (i >= N) return;
    float px = xs[3 * i], py = xs[3 * i + 1], pz = xs[3 * i + 2];
    float s = lv.scale[l];
    int res = lv.res[l];
    float fx = px * s + 0.5f, fy = py * s + 0.5f, fz = pz * s + 0.5f;
    float gx = floorf(fx), gy = floorf(fy), gz = floorf(fz);
    float wx = fx - gx, wy = fy - gy, wz = fz - gz;
    int cx = (int)gx, cy = (int)gy, cz = (int)gz;
    unsigned idx[8];
    if ((lv.dense_mask >> l) & 1u) {
        int r1 = res - 1;
        int x0 = min(cx, r1), x1 = min(cx + 1, r1);
        int y0 = min(cy, r1), y1 = min(cy + 1, r1);
        int z0 = min(cz, r1), z1 = min(cz + 1, r1);
        int rr = res * res;
        idx[0] = x0 + y0 * res + z0 * rr; idx[1] = x0 + y0 * res + z1 * rr;
        idx[2] = x0 + y1 * res + z0 * rr; idx[3] = x0 + y1 * res + z1 * rr;
        idx[4] = x1 + y0 * res + z0 * rr; idx[5] = x1 + y0 * res + z1 * rr;
        idx[6] = x1 + y1 * res + z0 * rr; idx[7] = x1 + y1 * res + z1 * rr;
    } else {
        unsigned hx0 = (unsigned)cx, hx1 = (unsigned)(cx + 1);
        unsigned hy0 = (unsigned)cy * 2654435761u, hy1 = (unsigned)(cy + 1) * 2654435761u;
        unsigned hz0 = (unsigned)cz * 805459861u,  hz1 = (unsigned)(cz + 1) * 805459861u;
        idx[0] = (hx0^hy0^hz0) & (T_SIZE-1); idx[1] = (hx0^hy0^hz1) & (T_SIZE-1);
        idx[2] = (hx0^hy1^hz0) & (T_SIZE-1); idx[3] = (hx0^hy1^hz1) & (T_SIZE-1);
        idx[4] = (hx1^hy0^hz0) & (T_SIZE-1); idx[5] = (hx1^hy0^hz1) & (T_SIZE-1);
        idx[6] = (hx1^hy1^hz0) & (T_SIZE-1); idx[7] = (hx1^hy1^hz1) & (T_SIZE-1);
    }
    const float2* tl = table + (size_t)l * T_SIZE;
    float wx0 = 1.f - wx, wy0 = 1.f - wy, wz0 = 1.f - wz;
    float wcs[8] = {wx0*wy0*wz0, wx0*wy0*wz, wx0*wy*wz0, wx0*wy*wz,
                    wx*wy0*wz0,  wx*wy0*wz,  wx*wy*wz0,  wx*wy*wz};
    float f0 = 0.f, f1 = 0.f;
#pragma unroll
    for (int c = 0; c < 8; ++c) {
        float2 v = tl[idx[c]];
        f0 += wcs[c] * v.x; f1 += wcs[c] * v.y;
    }
    h2 r; r[0] = (_Float16)f0; r[1] = (_Float16)f1;
    enc2[(size_t)l * N + i] = r;
}

extern "C" void kernel_launch(void* const* d_in, const int* in_sizes, int n_in,
                              void* d_out, int out_size, void* d_ws, size_t ws_size,
                              hipStream_t stream) {
    const float* x     = (const float*)d_in[0];
    const float* table = (const float*)d_in[1];
    const float* w1    = (const float*)d_in[2];
    const float* w2    = (const float*)d_in[3];
    const float* w3    = (const float*)d_in[4];
    const float* w4    = (const float*)d_in[5];
    float* out = (float*)d_out;
    const int N = in_sizes[0] / 3;                 // 1<<20

    Levels lv;
    lv.dense_mask = 0;
    const double pls = exp2(log2(2048.0 / 16.0) / 15.0);
    const double lg  = log2(pls);
    for (int l = 0; l < 16; ++l) {
        double sc = exp2((double)l * lg) * 16.0 - 1.0;
        int res = (int)ceil(sc) + 1;
        lv.scale[l] = (float)sc;
        lv.res[l]   = res;
        if ((long long)res * res * res <= (long long)T_SIZE) lv.dense_mask |= (1u << l);
    }

    const size_t encBytes   = (size_t)16 * N * 4;        // 64 MB
    const size_t tableBytes = (size_t)16 * T_SIZE * 4;   // 33.5 MB
    h2* enc2 = (h2*)d_ws;

    const int ptBlocks = (N + 255) / 256;                // 4096
    dim3 encGrid(ptBlocks, 16);                          // y = level, slow-varying

    if (ws_size >= encBytes + tableBytes) {
        h2* table16 = (h2*)((char*)d_ws + encBytes);
        const int total4 = 16 * T_SIZE / 4;
        hipLaunchKernelGGL(convert_table_kernel, dim3((total4 + 255) / 256), dim3(256), 0,
                           stream, (const float2*)table, table16, total4);
        hipLaunchKernelGGL(encode_kernel, encGrid, dim3(256), 0, stream,
                           x, (const h2*)table16, enc2, lv, N);
    } else {
        hipLaunchKernelGGL(encode_kernel_f32, encGrid, dim3(256), 0, stream,
                           x, (const float2*)table, enc2, lv, N);
    }

    const int mlpBlocks = 1024;                          // 4 blocks/CU (LDS-capped)
    const int tiles = N / 256 / mlpBlocks;               // 4
    hipLaunchKernelGGL(mlp_kernel, dim3(mlpBlocks), dim3(256), 0, stream,
                       enc2, w1, w2, w3, w4, out, tiles, N);
}